// Round 1
// baseline (424.347 us; speedup 1.0000x reference)
//
#include <hip/hip_runtime.h>
#include <hip/hip_bf16.h>

#define T_TOK 4096
#define H_DIM 1024
#define DFF_D 2048
#define E_NUM 8
#define K_TOP 2

#define BM 64
#define BN 64
#define BK 32
#define PAD 56   // 112B row stride: 16B-aligned, 2-way-max bank aliasing (free)

typedef __attribute__((ext_vector_type(8))) short s16x8;
typedef __attribute__((ext_vector_type(4))) float f32x4;

__device__ __forceinline__ ushort f2bf(float f) {
    unsigned u = __float_as_uint(f);
    u = (u + 0x7FFFu + ((u >> 16) & 1u)) >> 16;  // RNE
    return (ushort)u;
}

__device__ __forceinline__ void stage8_cvt(ushort* dst, const float* src) {
    float4 a = *(const float4*)(src);
    float4 b = *(const float4*)(src + 4);
    union { ushort us[8]; uint4 q; } p;
    p.us[0] = f2bf(a.x); p.us[1] = f2bf(a.y); p.us[2] = f2bf(a.z); p.us[3] = f2bf(a.w);
    p.us[4] = f2bf(b.x); p.us[5] = f2bf(b.y); p.us[6] = f2bf(b.z); p.us[7] = f2bf(b.w);
    *(uint4*)dst = p.q;
}

// ---------------- gating + routing ----------------
__global__ __launch_bounds__(64) void gate_kernel(
    const float* __restrict__ x, const float* __restrict__ Wg,
    int* __restrict__ cnt, int* __restrict__ tok_list,
    int* __restrict__ slot_list, float* __restrict__ wt_slot)
{
    const int t = blockIdx.x;
    const int lane = threadIdx.x;
    const float* xr = x + (size_t)t * H_DIM;
    float xv[16];
    #pragma unroll
    for (int j = 0; j < 16; ++j) xv[j] = xr[j * 64 + lane];

    float score[E_NUM];
    #pragma unroll
    for (int e = 0; e < E_NUM; ++e) {
        const float* wr = Wg + e * H_DIM;
        float p = 0.f;
        #pragma unroll
        for (int j = 0; j < 16; ++j) p += xv[j] * wr[j * 64 + lane];
        #pragma unroll
        for (int s = 32; s >= 1; s >>= 1) p += __shfl_xor(p, s, 64);
        score[e] = p;
    }
    if (lane == 0) {
        int i0 = 0;
        #pragma unroll
        for (int e = 1; e < E_NUM; ++e) if (score[e] > score[i0]) i0 = e;
        int i1 = (i0 == 0) ? 1 : 0;
        #pragma unroll
        for (int e = 0; e < E_NUM; ++e)
            if (e != i0 && score[e] > score[i1]) i1 = e;
        float v0 = score[i0], v1 = score[i1];
        float e1 = expf(v1 - v0);
        float w0 = 1.f / (1.f + e1);
        float w1 = e1 / (1.f + e1);

        int p0 = atomicAdd(&cnt[i0], 1);
        tok_list[i0 * T_TOK + p0] = t;
        slot_list[i0 * T_TOK + p0] = t * K_TOP + 0;
        wt_slot[t * K_TOP + 0] = w0;
        int p1 = atomicAdd(&cnt[i1], 1);
        tok_list[i1 * T_TOK + p1] = t;
        slot_list[i1 * T_TOK + p1] = t * K_TOP + 1;
        wt_slot[t * K_TOP + 1] = w1;
    }
}

// ---------------- up projection: h = w * silu(xW1^T+b1) * (xW2^T+b2) ----------------
__global__ __launch_bounds__(256) void up_kernel(
    const float* __restrict__ x,
    const float* __restrict__ W1, const float* __restrict__ b1,
    const float* __restrict__ W2, const float* __restrict__ b2,
    const int* __restrict__ cnt, const int* __restrict__ tok_list,
    const int* __restrict__ slot_list, const float* __restrict__ wt_slot,
    ushort* __restrict__ h)
{
    const int e = blockIdx.z;
    const int M = cnt[e];
    const int mbase = blockIdx.y * BM;
    if (mbase >= M) return;
    const int nbase = blockIdx.x * BN;
    const int tid = threadIdx.x;
    const int lane = tid & 63;
    const int w = tid >> 6;

    __shared__ ushort As[BM][PAD];
    __shared__ ushort B1s[BN][PAD];
    __shared__ ushort B2s[BN][PAD];

    const int srow = tid >> 2;
    const int scol = (tid & 3) * 8;
    const int lpos = mbase + srow;
    const int atok = (lpos < M) ? tok_list[e * T_TOK + lpos] : 0;
    const float* aptr  = x  + (size_t)atok * H_DIM + scol;
    const float* b1ptr = W1 + ((size_t)e * DFF_D + (nbase + srow)) * H_DIM + scol;
    const float* b2ptr = W2 + ((size_t)e * DFF_D + (nbase + srow)) * H_DIM + scol;

    const f32x4 zero = {0.f, 0.f, 0.f, 0.f};
    f32x4 accg[4], accv[4];
    #pragma unroll
    for (int i = 0; i < 4; ++i) { accg[i] = zero; accv[i] = zero; }

    const int r16 = lane & 15;
    const int kb8 = (lane >> 4) * 8;

    for (int kk = 0; kk < H_DIM; kk += BK) {
        stage8_cvt(&As[srow][scol],  aptr  + kk);
        stage8_cvt(&B1s[srow][scol], b1ptr + kk);
        stage8_cvt(&B2s[srow][scol], b2ptr + kk);
        __syncthreads();
        s16x8 bf1 = *(const s16x8*)&B1s[w * 16 + r16][kb8];
        s16x8 bf2 = *(const s16x8*)&B2s[w * 16 + r16][kb8];
        #pragma unroll
        for (int mi = 0; mi < 4; ++mi) {
            s16x8 af = *(const s16x8*)&As[mi * 16 + r16][kb8];
            accg[mi] = __builtin_amdgcn_mfma_f32_16x16x32_bf16(af, bf1, accg[mi], 0, 0, 0);
            accv[mi] = __builtin_amdgcn_mfma_f32_16x16x32_bf16(af, bf2, accv[mi], 0, 0, 0);
        }
        __syncthreads();
    }

    const int col = nbase + w * 16 + r16;
    const float bb1 = b1[e * DFF_D + col];
    const float bb2 = b2[e * DFF_D + col];
    #pragma unroll
    for (int mi = 0; mi < 4; ++mi) {
        #pragma unroll
        for (int j = 0; j < 4; ++j) {
            int p = mbase + mi * 16 + (lane >> 4) * 4 + j;
            if (p < M) {
                int slot = slot_list[e * T_TOK + p];
                float wgt = wt_slot[slot];
                float g = accg[mi][j] + bb1;
                float v = accv[mi][j] + bb2;
                float s = g / (1.f + __expf(-g));
                h[(size_t)slot * DFF_D + col] = f2bf(wgt * s * v);
            }
        }
    }
}

// ---------------- down projection + scatter-add ----------------
__global__ __launch_bounds__(256) void down_kernel(
    const ushort* __restrict__ h,
    const float* __restrict__ W3, const float* __restrict__ b3,
    const int* __restrict__ cnt, const int* __restrict__ slot_list,
    const float* __restrict__ wt_slot, float* __restrict__ out)
{
    const int e = blockIdx.z;
    const int M = cnt[e];
    const int mbase = blockIdx.y * BM;
    if (mbase >= M) return;
    const int nbase = blockIdx.x * BN;
    const int tid = threadIdx.x;
    const int lane = tid & 63;
    const int w = tid >> 6;

    __shared__ ushort As[BM][PAD];
    __shared__ ushort Bs[BN][PAD];

    const int srow = tid >> 2;
    const int scol = (tid & 3) * 8;
    const int lpos = mbase + srow;
    const int aslot = (lpos < M) ? slot_list[e * T_TOK + lpos] : 0;
    const ushort* aptr = h + (size_t)aslot * DFF_D + scol;
    const float* bptr = W3 + ((size_t)e * H_DIM + (nbase + srow)) * DFF_D + scol;

    const f32x4 zero = {0.f, 0.f, 0.f, 0.f};
    f32x4 acc[4];
    #pragma unroll
    for (int i = 0; i < 4; ++i) acc[i] = zero;

    const int r16 = lane & 15;
    const int kb8 = (lane >> 4) * 8;

    for (int kk = 0; kk < DFF_D; kk += BK) {
        *(uint4*)&As[srow][scol] = *(const uint4*)(aptr + kk);
        stage8_cvt(&Bs[srow][scol], bptr + kk);
        __syncthreads();
        s16x8 bf = *(const s16x8*)&Bs[w * 16 + r16][kb8];
        #pragma unroll
        for (int mi = 0; mi < 4; ++mi) {
            s16x8 af = *(const s16x8*)&As[mi * 16 + r16][kb8];
            acc[mi] = __builtin_amdgcn_mfma_f32_16x16x32_bf16(af, bf, acc[mi], 0, 0, 0);
        }
        __syncthreads();
    }

    const int col = nbase + w * 16 + r16;
    const float bb3 = b3[e * H_DIM + col];
    #pragma unroll
    for (int mi = 0; mi < 4; ++mi) {
        #pragma unroll
        for (int j = 0; j < 4; ++j) {
            int p = mbase + mi * 16 + (lane >> 4) * 4 + j;
            if (p < M) {
                int slot = slot_list[e * T_TOK + p];
                float wgt = wt_slot[slot];
                int t = slot / K_TOP;
                atomicAdd(&out[(size_t)t * H_DIM + col], acc[mi][j] + wgt * bb3);
            }
        }
    }
}

extern "C" void kernel_launch(void* const* d_in, const int* in_sizes, int n_in,
                              void* d_out, int out_size, void* d_ws, size_t ws_size,
                              hipStream_t stream) {
    const float* x  = (const float*)d_in[0];
    const float* Wg = (const float*)d_in[1];
    const float* W1 = (const float*)d_in[2];
    const float* b1 = (const float*)d_in[3];
    const float* W2 = (const float*)d_in[4];
    const float* b2 = (const float*)d_in[5];
    const float* W3 = (const float*)d_in[6];
    const float* b3 = (const float*)d_in[7];
    float* out = (float*)d_out;

    char* ws = (char*)d_ws;
    int*   cnt       = (int*)(ws + 0);
    int*   tok_list  = (int*)(ws + 1024);
    int*   slot_list = (int*)(ws + 1024 + E_NUM * T_TOK * 4);
    float* wt_slot   = (float*)(ws + 1024 + 2 * E_NUM * T_TOK * 4);
    ushort* h        = (ushort*)(ws + (1 << 19));   // 32 MB bf16 [T*K, DFF]

    hipMemsetAsync(ws, 0, 1024, stream);                                  // cnt
    hipMemsetAsync(d_out, 0, (size_t)T_TOK * H_DIM * sizeof(float), stream);

    gate_kernel<<<T_TOK, 64, 0, stream>>>(x, Wg, cnt, tok_list, slot_list, wt_slot);

    dim3 gup(DFF_D / BN, T_TOK / BM, E_NUM);
    up_kernel<<<gup, 256, 0, stream>>>(x, W1, b1, W2, b2, cnt, tok_list, slot_list, wt_slot, h);

    dim3 gdn(H_DIM / BN, T_TOK / BM, E_NUM);
    down_kernel<<<gdn, 256, 0, stream>>>(h, W3, b3, cnt, slot_list, wt_slot, out);
}

// Round 2
// 401.338 us; speedup vs baseline: 1.0573x; 1.0573x over previous
//
#include <hip/hip_runtime.h>
#include <hip/hip_bf16.h>

#define T_TOK 4096
#define H_DIM 1024
#define DFF_D 2048
#define E_NUM 8
#define K_TOP 2

typedef __attribute__((ext_vector_type(8))) short s16x8;
typedef __attribute__((ext_vector_type(4))) float f32x4;

__device__ __forceinline__ ushort f2bf(float f) {
    unsigned u = __float_as_uint(f);
    u = (u + 0x7FFFu + ((u >> 16) & 1u)) >> 16;  // RNE
    return (ushort)u;
}

__device__ __forceinline__ void glds16(const ushort* g, ushort* l) {
    __builtin_amdgcn_global_load_lds(
        (const __attribute__((address_space(1))) unsigned*)g,
        (__attribute__((address_space(3))) unsigned*)l, 16, 0, 0);
}

// swizzled LDS fragment read: tile stored [rows][64] bf16 (128B rows),
// source was staged with matching inverse swizzle.
__device__ __forceinline__ s16x8 lds_frag(const ushort* base, int row, int bytecol) {
    int byte = row * 128 + (bytecol ^ ((row & 7) << 4));
    return *(const s16x8*)((const char*)base + byte);
}

// ---------------- fp32 -> bf16 bulk convert ----------------
__global__ __launch_bounds__(256) void cvt_kernel(
    const float* __restrict__ in, ushort* __restrict__ out, int n8)
{
    int i = blockIdx.x * blockDim.x + threadIdx.x;
    const int stride = gridDim.x * blockDim.x;
    for (; i < n8; i += stride) {
        const float* p = in + (size_t)i * 8;
        float4 a = ((const float4*)p)[0];
        float4 b = ((const float4*)p)[1];
        union { ushort us[8]; uint4 q; } o;
        o.us[0] = f2bf(a.x); o.us[1] = f2bf(a.y); o.us[2] = f2bf(a.z); o.us[3] = f2bf(a.w);
        o.us[4] = f2bf(b.x); o.us[5] = f2bf(b.y); o.us[6] = f2bf(b.z); o.us[7] = f2bf(b.w);
        ((uint4*)out)[i] = o.q;
    }
}

// ---------------- gating + routing ----------------
__global__ __launch_bounds__(64) void gate_kernel(
    const float* __restrict__ x, const float* __restrict__ Wg,
    int* __restrict__ cnt, int* __restrict__ tok_list,
    int* __restrict__ slot_list, float* __restrict__ wt_slot)
{
    const int t = blockIdx.x;
    const int lane = threadIdx.x;
    const float* xr = x + (size_t)t * H_DIM;
    float xv[16];
    #pragma unroll
    for (int j = 0; j < 16; ++j) xv[j] = xr[j * 64 + lane];

    float score[E_NUM];
    #pragma unroll
    for (int e = 0; e < E_NUM; ++e) {
        const float* wr = Wg + e * H_DIM;
        float p = 0.f;
        #pragma unroll
        for (int j = 0; j < 16; ++j) p += xv[j] * wr[j * 64 + lane];
        #pragma unroll
        for (int s = 32; s >= 1; s >>= 1) p += __shfl_xor(p, s, 64);
        score[e] = p;
    }
    if (lane == 0) {
        int i0 = 0;
        #pragma unroll
        for (int e = 1; e < E_NUM; ++e) if (score[e] > score[i0]) i0 = e;
        int i1 = (i0 == 0) ? 1 : 0;
        #pragma unroll
        for (int e = 0; e < E_NUM; ++e)
            if (e != i0 && score[e] > score[i1]) i1 = e;
        float e1 = expf(score[i1] - score[i0]);
        float w0 = 1.f / (1.f + e1);
        float w1 = e1 / (1.f + e1);

        int p0 = atomicAdd(&cnt[i0], 1);
        tok_list[i0 * T_TOK + p0] = t;
        slot_list[i0 * T_TOK + p0] = t * K_TOP + 0;
        wt_slot[t * K_TOP + 0] = w0;
        int p1 = atomicAdd(&cnt[i1], 1);
        tok_list[i1 * T_TOK + p1] = t;
        slot_list[i1 * T_TOK + p1] = t * K_TOP + 1;
        wt_slot[t * K_TOP + 1] = w1;
    }
}

// ---------------- up: h = w * silu(xW1^T+b1) * (xW2^T+b2), 128x(64+64) tile ----------------
__global__ __launch_bounds__(256) void up_kernel(
    const ushort* __restrict__ xbf,
    const ushort* __restrict__ w1bf, const float* __restrict__ b1,
    const ushort* __restrict__ w2bf, const float* __restrict__ b2,
    const int* __restrict__ cnt, const int* __restrict__ tok_list,
    const int* __restrict__ slot_list, const float* __restrict__ wt_slot,
    ushort* __restrict__ h)
{
    const int e = blockIdx.z;
    const int M = cnt[e];
    const int mbase = blockIdx.y * 128;
    if (mbase >= M) return;
    const int nbase = blockIdx.x * 64;
    const int tid = threadIdx.x;
    const int lane = tid & 63;
    const int w = tid >> 6;

    __shared__ ushort As[128 * 64];
    __shared__ ushort B1s[64 * 64];
    __shared__ ushort B2s[64 * 64];

    // per-lane staging sources with inverse swizzle baked into the column
    const ushort* srcA[4];
    const ushort* srcB1[2];
    const ushort* srcB2[2];
    #pragma unroll
    for (int j = 0; j < 4; ++j) {
        int o = j * 4096 + w * 1024 + lane * 16;       // byte pos in linear A tile
        int r = o >> 7;
        int cb = (o & 127) ^ ((r & 7) << 4);
        int lpos = mbase + r; if (lpos > M - 1) lpos = M - 1;
        int tok = tok_list[e * T_TOK + lpos];
        srcA[j] = xbf + (size_t)tok * H_DIM + (cb >> 1);
    }
    #pragma unroll
    for (int j = 0; j < 2; ++j) {
        int o = j * 4096 + w * 1024 + lane * 16;
        int r = o >> 7;
        int cb = (o & 127) ^ ((r & 7) << 4);
        srcB1[j] = w1bf + ((size_t)e * DFF_D + nbase + r) * H_DIM + (cb >> 1);
        srcB2[j] = w2bf + ((size_t)e * DFF_D + nbase + r) * H_DIM + (cb >> 1);
    }

    const f32x4 zero = {0.f, 0.f, 0.f, 0.f};
    f32x4 accg[2][4], accv[2][4];
    #pragma unroll
    for (int mi = 0; mi < 2; ++mi)
        #pragma unroll
        for (int ni = 0; ni < 4; ++ni) { accg[mi][ni] = zero; accv[mi][ni] = zero; }

    const int r16 = lane & 15;
    const int g4  = lane >> 4;
    const int cb0 = g4 * 16;

    for (int k0 = 0; k0 < H_DIM; k0 += 64) {
        #pragma unroll
        for (int j = 0; j < 4; ++j)
            glds16(srcA[j] + k0, &As[j * 2048 + w * 512]);
        #pragma unroll
        for (int j = 0; j < 2; ++j) {
            glds16(srcB1[j] + k0, &B1s[j * 2048 + w * 512]);
            glds16(srcB2[j] + k0, &B2s[j * 2048 + w * 512]);
        }
        __syncthreads();
        #pragma unroll
        for (int kk = 0; kk < 2; ++kk) {
            s16x8 bf1[4], bf2[4];
            #pragma unroll
            for (int ni = 0; ni < 4; ++ni) {
                bf1[ni] = lds_frag(B1s, ni * 16 + r16, kk * 64 + cb0);
                bf2[ni] = lds_frag(B2s, ni * 16 + r16, kk * 64 + cb0);
            }
            #pragma unroll
            for (int mi = 0; mi < 2; ++mi) {
                s16x8 af = lds_frag(As, w * 32 + mi * 16 + r16, kk * 64 + cb0);
                #pragma unroll
                for (int ni = 0; ni < 4; ++ni) {
                    accg[mi][ni] = __builtin_amdgcn_mfma_f32_16x16x32_bf16(af, bf1[ni], accg[mi][ni], 0, 0, 0);
                    accv[mi][ni] = __builtin_amdgcn_mfma_f32_16x16x32_bf16(af, bf2[ni], accv[mi][ni], 0, 0, 0);
                }
            }
        }
        __syncthreads();
    }

    #pragma unroll
    for (int mi = 0; mi < 2; ++mi) {
        #pragma unroll
        for (int j = 0; j < 4; ++j) {
            int p = mbase + w * 32 + mi * 16 + g4 * 4 + j;
            if (p < M) {
                int slot = slot_list[e * T_TOK + p];
                float wgt = wt_slot[slot];
                #pragma unroll
                for (int ni = 0; ni < 4; ++ni) {
                    int col = nbase + ni * 16 + r16;
                    float g = accg[mi][ni][j] + b1[e * DFF_D + col];
                    float v = accv[mi][ni][j] + b2[e * DFF_D + col];
                    float s = g / (1.f + __expf(-g));
                    h[(size_t)slot * DFF_D + col] = f2bf(wgt * s * v);
                }
            }
        }
    }
}

// ---------------- down: out += h @ W3^T (+ w*b3), 128x128 tile ----------------
__global__ __launch_bounds__(256) void down_kernel(
    const ushort* __restrict__ h,
    const ushort* __restrict__ w3bf, const float* __restrict__ b3,
    const int* __restrict__ cnt, const int* __restrict__ slot_list,
    const float* __restrict__ wt_slot, float* __restrict__ out)
{
    const int e = blockIdx.z;
    const int M = cnt[e];
    const int mbase = blockIdx.y * 128;
    if (mbase >= M) return;
    const int nbase = blockIdx.x * 128;
    const int tid = threadIdx.x;
    const int lane = tid & 63;
    const int w = tid >> 6;
    const int wr = w >> 1, wc = w & 1;

    __shared__ ushort As[128 * 64];
    __shared__ ushort Bs[128 * 64];

    const ushort* srcA[4];
    const ushort* srcB[4];
    #pragma unroll
    for (int j = 0; j < 4; ++j) {
        int o = j * 4096 + w * 1024 + lane * 16;
        int r = o >> 7;
        int cb = (o & 127) ^ ((r & 7) << 4);
        int lpos = mbase + r; if (lpos > M - 1) lpos = M - 1;
        int slot = slot_list[e * T_TOK + lpos];
        srcA[j] = h + (size_t)slot * DFF_D + (cb >> 1);
        srcB[j] = w3bf + ((size_t)e * H_DIM + nbase + r) * DFF_D + (cb >> 1);
    }

    const f32x4 zero = {0.f, 0.f, 0.f, 0.f};
    f32x4 acc[4][4];
    #pragma unroll
    for (int mi = 0; mi < 4; ++mi)
        #pragma unroll
        for (int ni = 0; ni < 4; ++ni) acc[mi][ni] = zero;

    const int r16 = lane & 15;
    const int g4  = lane >> 4;
    const int cb0 = g4 * 16;

    for (int k0 = 0; k0 < DFF_D; k0 += 64) {
        #pragma unroll
        for (int j = 0; j < 4; ++j) {
            glds16(srcA[j] + k0, &As[j * 2048 + w * 512]);
            glds16(srcB[j] + k0, &Bs[j * 2048 + w * 512]);
        }
        __syncthreads();
        #pragma unroll
        for (int kk = 0; kk < 2; ++kk) {
            s16x8 bf[4];
            #pragma unroll
            for (int ni = 0; ni < 4; ++ni)
                bf[ni] = lds_frag(Bs, wc * 64 + ni * 16 + r16, kk * 64 + cb0);
            #pragma unroll
            for (int mi = 0; mi < 4; ++mi) {
                s16x8 af = lds_frag(As, wr * 64 + mi * 16 + r16, kk * 64 + cb0);
                #pragma unroll
                for (int ni = 0; ni < 4; ++ni)
                    acc[mi][ni] = __builtin_amdgcn_mfma_f32_16x16x32_bf16(af, bf[ni], acc[mi][ni], 0, 0, 0);
            }
        }
        __syncthreads();
    }

    #pragma unroll
    for (int mi = 0; mi < 4; ++mi) {
        #pragma unroll
        for (int j = 0; j < 4; ++j) {
            int p = mbase + wr * 64 + mi * 16 + g4 * 4 + j;
            if (p < M) {
                int slot = slot_list[e * T_TOK + p];
                float wgt = wt_slot[slot];
                int t = slot >> 1;   // K_TOP == 2
                #pragma unroll
                for (int ni = 0; ni < 4; ++ni) {
                    int col = nbase + wc * 64 + ni * 16 + r16;
                    atomicAdd(&out[(size_t)t * H_DIM + col],
                              acc[mi][ni][j] + wgt * b3[e * H_DIM + col]);
                }
            }
        }
    }
}

extern "C" void kernel_launch(void* const* d_in, const int* in_sizes, int n_in,
                              void* d_out, int out_size, void* d_ws, size_t ws_size,
                              hipStream_t stream) {
    const float* x  = (const float*)d_in[0];
    const float* Wg = (const float*)d_in[1];
    const float* W1 = (const float*)d_in[2];
    const float* b1 = (const float*)d_in[3];
    const float* W2 = (const float*)d_in[4];
    const float* b2 = (const float*)d_in[5];
    const float* W3 = (const float*)d_in[6];
    const float* b3 = (const float*)d_in[7];
    float* out = (float*)d_out;

    char* ws = (char*)d_ws;
    int*   cnt       = (int*)(ws);
    int*   tok_list  = (int*)(ws + 1024);
    int*   slot_list = (int*)(ws + 1024 + E_NUM * T_TOK * 4);
    float* wt_slot   = (float*)(ws + 1024 + 2 * E_NUM * T_TOK * 4);
    ushort* xbf  = (ushort*)(ws + (size_t)1  * (1u << 20));   // 8 MB
    ushort* w1bf = (ushort*)(ws + (size_t)16 * (1u << 20));   // 32 MB
    ushort* w2bf = (ushort*)(ws + (size_t)48 * (1u << 20));   // 32 MB
    ushort* hbuf = (ushort*)(ws + (size_t)80 * (1u << 20));   // 32 MB -> total 112 MB
    ushort* w3bf = w1bf;   // reuse W1 region after up_kernel (stream-ordered)

    hipMemsetAsync(cnt, 0, 1024, stream);
    hipMemsetAsync(d_out, 0, (size_t)T_TOK * H_DIM * sizeof(float), stream);

    cvt_kernel<<<1024, 256, 0, stream>>>(x,  xbf,  T_TOK * H_DIM / 8);
    cvt_kernel<<<2048, 256, 0, stream>>>(W1, w1bf, E_NUM * DFF_D * H_DIM / 8);
    cvt_kernel<<<2048, 256, 0, stream>>>(W2, w2bf, E_NUM * DFF_D * H_DIM / 8);

    gate_kernel<<<T_TOK, 64, 0, stream>>>(x, Wg, cnt, tok_list, slot_list, wt_slot);

    dim3 gup(DFF_D / 64, T_TOK / 128, E_NUM);
    up_kernel<<<gup, 256, 0, stream>>>(xbf, w1bf, b1, w2bf, b2, cnt, tok_list,
                                       slot_list, wt_slot, hbuf);

    cvt_kernel<<<2048, 256, 0, stream>>>(W3, w3bf, E_NUM * H_DIM * DFF_D / 8);

    dim3 gdn(H_DIM / 128, T_TOK / 128, E_NUM);
    down_kernel<<<gdn, 256, 0, stream>>>(hbuf, w3bf, b3, cnt, slot_list, wt_slot, out);
}

// Round 3
// 397.003 us; speedup vs baseline: 1.0689x; 1.0109x over previous
//
#include <hip/hip_runtime.h>
#include <hip/hip_bf16.h>

#define T_TOK 4096
#define H_DIM 1024
#define DFF_D 2048
#define E_NUM 8
#define K_TOP 2
#define KSPLIT 2

typedef __attribute__((ext_vector_type(8))) short s16x8;
typedef __attribute__((ext_vector_type(4))) float f32x4;

__device__ __forceinline__ ushort f2bf(float f) {
    unsigned u = __float_as_uint(f);
    u = (u + 0x7FFFu + ((u >> 16) & 1u)) >> 16;  // RNE
    return (ushort)u;
}

__device__ __forceinline__ void glds16(const ushort* g, ushort* l) {
    __builtin_amdgcn_global_load_lds(
        (const __attribute__((address_space(1))) unsigned*)g,
        (__attribute__((address_space(3))) unsigned*)l, 16, 0, 0);
}

// swizzled LDS fragment read: tile stored [rows][64] bf16 (128B rows),
// source was staged with matching inverse swizzle.
__device__ __forceinline__ s16x8 lds_frag(const ushort* base, int row, int bytecol) {
    int byte = row * 128 + (bytecol ^ ((row & 7) << 4));
    return *(const s16x8*)((const char*)base + byte);
}

__device__ __forceinline__ void cvt8(const float* p, ushort* dst, size_t i) {
    float4 a = ((const float4*)(p + i * 8))[0];
    float4 b = ((const float4*)(p + i * 8))[1];
    union { ushort us[8]; uint4 q; } o;
    o.us[0] = f2bf(a.x); o.us[1] = f2bf(a.y); o.us[2] = f2bf(a.z); o.us[3] = f2bf(a.w);
    o.us[4] = f2bf(b.x); o.us[5] = f2bf(b.y); o.us[6] = f2bf(b.z); o.us[7] = f2bf(b.w);
    ((uint4*)dst)[i] = o.q;
}

// ---------------- fp32 -> bf16 bulk converts ----------------
__global__ __launch_bounds__(256) void cvt_kernel(
    const float* __restrict__ in, ushort* __restrict__ out, int n8)
{
    int i = blockIdx.x * blockDim.x + threadIdx.x;
    const int stride = gridDim.x * blockDim.x;
    for (; i < n8; i += stride) cvt8(in, out, i);
}

__global__ __launch_bounds__(256) void cvt3_kernel(
    const float* __restrict__ x,  ushort* __restrict__ xbf,
    const float* __restrict__ W1, ushort* __restrict__ w1bf,
    const float* __restrict__ W2, ushort* __restrict__ w2bf)
{
    const int nW = E_NUM * DFF_D * H_DIM / 8;   // 2,097,152
    const int nX = T_TOK * H_DIM / 8;           //   524,288
    const int total = 2 * nW + nX;
    int i = blockIdx.x * blockDim.x + threadIdx.x;
    const int stride = gridDim.x * blockDim.x;
    for (; i < total; i += stride) {
        if (i < nW)            cvt8(W1, w1bf, i);
        else if (i < 2 * nW)   cvt8(W2, w2bf, i - nW);
        else                   cvt8(x,  xbf,  i - 2 * nW);
    }
}

// ---------------- gating + routing ----------------
__global__ __launch_bounds__(64) void gate_kernel(
    const float* __restrict__ x, const float* __restrict__ Wg,
    int* __restrict__ cnt, int* __restrict__ tok_list,
    int* __restrict__ slot_list, float* __restrict__ wt_slot)
{
    const int t = blockIdx.x;
    const int lane = threadIdx.x;
    const float* xr = x + (size_t)t * H_DIM;
    float xv[16];
    #pragma unroll
    for (int j = 0; j < 16; ++j) xv[j] = xr[j * 64 + lane];

    float score[E_NUM];
    #pragma unroll
    for (int e = 0; e < E_NUM; ++e) {
        const float* wr = Wg + e * H_DIM;
        float p = 0.f;
        #pragma unroll
        for (int j = 0; j < 16; ++j) p += xv[j] * wr[j * 64 + lane];
        #pragma unroll
        for (int s = 32; s >= 1; s >>= 1) p += __shfl_xor(p, s, 64);
        score[e] = p;
    }
    if (lane == 0) {
        int i0 = 0;
        #pragma unroll
        for (int e = 1; e < E_NUM; ++e) if (score[e] > score[i0]) i0 = e;
        int i1 = (i0 == 0) ? 1 : 0;
        #pragma unroll
        for (int e = 0; e < E_NUM; ++e)
            if (e != i0 && score[e] > score[i1]) i1 = e;
        float e1 = expf(score[i1] - score[i0]);
        float w0 = 1.f / (1.f + e1);
        float w1 = e1 / (1.f + e1);

        int p0 = atomicAdd(&cnt[i0], 1);
        tok_list[i0 * T_TOK + p0] = t;
        slot_list[i0 * T_TOK + p0] = t * K_TOP + 0;
        wt_slot[t * K_TOP + 0] = w0;
        int p1 = atomicAdd(&cnt[i1], 1);
        tok_list[i1 * T_TOK + p1] = t;
        slot_list[i1 * T_TOK + p1] = t * K_TOP + 1;
        wt_slot[t * K_TOP + 1] = w1;
    }
}

// ---------------- up: h = w * silu(xW1^T+b1) * (xW2^T+b2), 128x(64+64) tile ----------------
__global__ __launch_bounds__(256) void up_kernel(
    const ushort* __restrict__ xbf,
    const ushort* __restrict__ w1bf, const float* __restrict__ b1,
    const ushort* __restrict__ w2bf, const float* __restrict__ b2,
    const int* __restrict__ cnt, const int* __restrict__ tok_list,
    const int* __restrict__ slot_list, const float* __restrict__ wt_slot,
    ushort* __restrict__ h)
{
    const int e = blockIdx.z;
    const int M = cnt[e];
    const int mbase = blockIdx.y * 128;
    if (mbase >= M) return;
    const int nbase = blockIdx.x * 64;
    const int tid = threadIdx.x;
    const int lane = tid & 63;
    const int w = tid >> 6;

    __shared__ ushort As[128 * 64];
    __shared__ ushort B1s[64 * 64];
    __shared__ ushort B2s[64 * 64];

    // per-lane staging sources with inverse swizzle baked into the column
    const ushort* srcA[4];
    const ushort* srcB1[2];
    const ushort* srcB2[2];
    #pragma unroll
    for (int j = 0; j < 4; ++j) {
        int o = j * 4096 + w * 1024 + lane * 16;       // byte pos in linear A tile
        int r = o >> 7;
        int cb = (o & 127) ^ ((r & 7) << 4);
        int lpos = mbase + r; if (lpos > M - 1) lpos = M - 1;
        int tok = tok_list[e * T_TOK + lpos];
        srcA[j] = xbf + (size_t)tok * H_DIM + (cb >> 1);
    }
    #pragma unroll
    for (int j = 0; j < 2; ++j) {
        int o = j * 4096 + w * 1024 + lane * 16;
        int r = o >> 7;
        int cb = (o & 127) ^ ((r & 7) << 4);
        srcB1[j] = w1bf + ((size_t)e * DFF_D + nbase + r) * H_DIM + (cb >> 1);
        srcB2[j] = w2bf + ((size_t)e * DFF_D + nbase + r) * H_DIM + (cb >> 1);
    }

    const f32x4 zero = {0.f, 0.f, 0.f, 0.f};
    f32x4 accg[2][4], accv[2][4];
    #pragma unroll
    for (int mi = 0; mi < 2; ++mi)
        #pragma unroll
        for (int ni = 0; ni < 4; ++ni) { accg[mi][ni] = zero; accv[mi][ni] = zero; }

    const int r16 = lane & 15;
    const int g4  = lane >> 4;
    const int cb0 = g4 * 16;

    for (int k0 = 0; k0 < H_DIM; k0 += 64) {
        #pragma unroll
        for (int j = 0; j < 4; ++j)
            glds16(srcA[j] + k0, &As[j * 2048 + w * 512]);
        #pragma unroll
        for (int j = 0; j < 2; ++j) {
            glds16(srcB1[j] + k0, &B1s[j * 2048 + w * 512]);
            glds16(srcB2[j] + k0, &B2s[j * 2048 + w * 512]);
        }
        __syncthreads();
        #pragma unroll
        for (int kk = 0; kk < 2; ++kk) {
            s16x8 bf1[4], bf2[4];
            #pragma unroll
            for (int ni = 0; ni < 4; ++ni) {
                bf1[ni] = lds_frag(B1s, ni * 16 + r16, kk * 64 + cb0);
                bf2[ni] = lds_frag(B2s, ni * 16 + r16, kk * 64 + cb0);
            }
            #pragma unroll
            for (int mi = 0; mi < 2; ++mi) {
                s16x8 af = lds_frag(As, w * 32 + mi * 16 + r16, kk * 64 + cb0);
                #pragma unroll
                for (int ni = 0; ni < 4; ++ni) {
                    accg[mi][ni] = __builtin_amdgcn_mfma_f32_16x16x32_bf16(af, bf1[ni], accg[mi][ni], 0, 0, 0);
                    accv[mi][ni] = __builtin_amdgcn_mfma_f32_16x16x32_bf16(af, bf2[ni], accv[mi][ni], 0, 0, 0);
                }
            }
        }
        __syncthreads();
    }

    #pragma unroll
    for (int mi = 0; mi < 2; ++mi) {
        #pragma unroll
        for (int j = 0; j < 4; ++j) {
            int p = mbase + w * 32 + mi * 16 + g4 * 4 + j;
            if (p < M) {
                int slot = slot_list[e * T_TOK + p];
                float wgt = wt_slot[slot];
                #pragma unroll
                for (int ni = 0; ni < 4; ++ni) {
                    int col = nbase + ni * 16 + r16;
                    float g = accg[mi][ni][j] + b1[e * DFF_D + col];
                    float v = accv[mi][ni][j] + b2[e * DFF_D + col];
                    float s = g / (1.f + __expf(-g));
                    h[(size_t)slot * DFF_D + col] = f2bf(wgt * s * v);
                }
            }
        }
    }
}

// ---------------- down: out += h @ W3^T (+ w*b3), 128x128 tile, split-K ----------------
__global__ __launch_bounds__(256) void down_kernel(
    const ushort* __restrict__ h,
    const ushort* __restrict__ w3bf, const float* __restrict__ b3,
    const int* __restrict__ cnt, const int* __restrict__ slot_list,
    const float* __restrict__ wt_slot, float* __restrict__ out)
{
    const int e  = blockIdx.z >> 1;
    const int kc = blockIdx.z & 1;
    const int M = cnt[e];
    const int mbase = blockIdx.y * 128;
    if (mbase >= M) return;
    const int nbase = blockIdx.x * 128;
    const int tid = threadIdx.x;
    const int lane = tid & 63;
    const int w = tid >> 6;
    const int wr = w >> 1, wc = w & 1;

    __shared__ ushort As[128 * 64];
    __shared__ ushort Bs[128 * 64];

    const int kbeg = kc * (DFF_D / KSPLIT);
    const ushort* srcA[4];
    const ushort* srcB[4];
    #pragma unroll
    for (int j = 0; j < 4; ++j) {
        int o = j * 4096 + w * 1024 + lane * 16;
        int r = o >> 7;
        int cb = (o & 127) ^ ((r & 7) << 4);
        int lpos = mbase + r; if (lpos > M - 1) lpos = M - 1;
        int slot = slot_list[e * T_TOK + lpos];
        srcA[j] = h + (size_t)slot * DFF_D + kbeg + (cb >> 1);
        srcB[j] = w3bf + ((size_t)e * H_DIM + nbase + r) * DFF_D + kbeg + (cb >> 1);
    }

    const f32x4 zero = {0.f, 0.f, 0.f, 0.f};
    f32x4 acc[4][4];
    #pragma unroll
    for (int mi = 0; mi < 4; ++mi)
        #pragma unroll
        for (int ni = 0; ni < 4; ++ni) acc[mi][ni] = zero;

    const int r16 = lane & 15;
    const int g4  = lane >> 4;
    const int cb0 = g4 * 16;

    for (int k0 = 0; k0 < DFF_D / KSPLIT; k0 += 64) {
        #pragma unroll
        for (int j = 0; j < 4; ++j) {
            glds16(srcA[j] + k0, &As[j * 2048 + w * 512]);
            glds16(srcB[j] + k0, &Bs[j * 2048 + w * 512]);
        }
        __syncthreads();
        #pragma unroll
        for (int kk = 0; kk < 2; ++kk) {
            s16x8 bf[4];
            #pragma unroll
            for (int ni = 0; ni < 4; ++ni)
                bf[ni] = lds_frag(Bs, wc * 64 + ni * 16 + r16, kk * 64 + cb0);
            #pragma unroll
            for (int mi = 0; mi < 4; ++mi) {
                s16x8 af = lds_frag(As, wr * 64 + mi * 16 + r16, kk * 64 + cb0);
                #pragma unroll
                for (int ni = 0; ni < 4; ++ni)
                    acc[mi][ni] = __builtin_amdgcn_mfma_f32_16x16x32_bf16(af, bf[ni], acc[mi][ni], 0, 0, 0);
            }
        }
        __syncthreads();
    }

    #pragma unroll
    for (int mi = 0; mi < 4; ++mi) {
        #pragma unroll
        for (int j = 0; j < 4; ++j) {
            int p = mbase + wr * 64 + mi * 16 + g4 * 4 + j;
            if (p < M) {
                int slot = slot_list[e * T_TOK + p];
                float wgt = wt_slot[slot];
                int t = slot >> 1;   // K_TOP == 2
                #pragma unroll
                for (int ni = 0; ni < 4; ++ni) {
                    int col = nbase + wc * 64 + ni * 16 + r16;
                    float v = acc[mi][ni][j];
                    if (kc == 0) v += wgt * b3[e * H_DIM + col];
                    atomicAdd(&out[(size_t)t * H_DIM + col], v);
                }
            }
        }
    }
}

extern "C" void kernel_launch(void* const* d_in, const int* in_sizes, int n_in,
                              void* d_out, int out_size, void* d_ws, size_t ws_size,
                              hipStream_t stream) {
    const float* x  = (const float*)d_in[0];
    const float* Wg = (const float*)d_in[1];
    const float* W1 = (const float*)d_in[2];
    const float* b1 = (const float*)d_in[3];
    const float* W2 = (const float*)d_in[4];
    const float* b2 = (const float*)d_in[5];
    const float* W3 = (const float*)d_in[6];
    const float* b3 = (const float*)d_in[7];
    float* out = (float*)d_out;

    char* ws = (char*)d_ws;
    int*   cnt       = (int*)(ws);
    int*   tok_list  = (int*)(ws + 1024);
    int*   slot_list = (int*)(ws + 1024 + E_NUM * T_TOK * 4);
    float* wt_slot   = (float*)(ws + 1024 + 2 * E_NUM * T_TOK * 4);
    ushort* xbf  = (ushort*)(ws + (size_t)1  * (1u << 20));   // 8 MB
    ushort* w1bf = (ushort*)(ws + (size_t)16 * (1u << 20));   // 32 MB
    ushort* w2bf = (ushort*)(ws + (size_t)48 * (1u << 20));   // 32 MB
    ushort* hbuf = (ushort*)(ws + (size_t)80 * (1u << 20));   // 32 MB -> total 112 MB
    ushort* w3bf = w1bf;   // reuse W1 region after up_kernel (stream-ordered)

    hipMemsetAsync(cnt, 0, 1024, stream);
    hipMemsetAsync(d_out, 0, (size_t)T_TOK * H_DIM * sizeof(float), stream);

    cvt3_kernel<<<2048, 256, 0, stream>>>(x, xbf, W1, w1bf, W2, w2bf);

    gate_kernel<<<T_TOK, 64, 0, stream>>>(x, Wg, cnt, tok_list, slot_list, wt_slot);

    dim3 gup(DFF_D / 64, T_TOK / 128, E_NUM);
    up_kernel<<<gup, 256, 0, stream>>>(xbf, w1bf, b1, w2bf, b2, cnt, tok_list,
                                       slot_list, wt_slot, hbuf);

    cvt_kernel<<<2048, 256, 0, stream>>>(W3, w3bf, E_NUM * H_DIM * DFF_D / 8);

    dim3 gdn(H_DIM / 128, T_TOK / 128, E_NUM * KSPLIT);
    down_kernel<<<gdn, 256, 0, stream>>>(hbuf, w3bf, b3, cnt, slot_list, wt_slot, out);
}